// Round 6
// baseline (80.440 us; speedup 1.0000x reference)
//
#include <hip/hip_runtime.h>

// ws layout (floats), all written unconditionally every launch (no memset needed):
//   [0 .. 3*NB_HM)                 hm partials per block:  {loss_sum, num_pos, cnt}
//   [REG_OFF .. REG_OFF+3*NB_REG)  reg partials per block: {wh_sum, off_sum, mask_sum}
#define NB_HM   2048
#define NB_REG  64
#define REG_OFF (3 * NB_HM)

typedef float f32x4 __attribute__((ext_vector_type(4)));

__device__ __forceinline__ float wave_sum(float v) {
    #pragma unroll
    for (int off = 32; off > 0; off >>= 1) v += __shfl_down(v, off, 64);
    return v;
}

__device__ __forceinline__ void block_reduce_store3(float a, float b, float c,
                                                    float* __restrict__ dst) {
    a = wave_sum(a); b = wave_sum(b); c = wave_sum(c);
    __shared__ float sa[8], sb[8], sc[8];
    int lane = threadIdx.x & 63;
    int wave = threadIdx.x >> 6;
    if (lane == 0) { sa[wave] = a; sb[wave] = b; sc[wave] = c; }
    __syncthreads();
    if (threadIdx.x == 0) {
        int nw = blockDim.x >> 6;
        float ta = 0.f, tb = 0.f, tc = 0.f;
        for (int w = 0; w < nw; ++w) { ta += sa[w]; tb += sb[w]; tc += sc[w]; }
        dst[0] = ta; dst[1] = tb; dst[2] = tc;
    }
}

// Focal-loss element (unchanged from the validated version).
__device__ __forceinline__ void hm_elem(float x, float gt, float& s_loss,
                                        unsigned& posc, unsigned& cntc) {
    bool pos = (gt == 1.0f);
    float e = __expf(-x);
    float p = __builtin_amdgcn_rcpf(1.0f + e);
    p = fminf(fmaxf(p, 1e-4f), 1.0f - 1e-4f);
    float arg = pos ? p : 1.0f - p;
    float a   = 1.0f - arg;
    float b   = pos ? 1.0f : 1.0f - gt;
    float b2  = b * b;
    float l   = __logf(arg);
    s_loss += (a * a) * (b2 * b2) * l;
    posc += (unsigned)__popcll(__ballot(pos));
    cntc += (unsigned)__popcll(__ballot(p > 0.3f));
}

// Hand-issued 16B load. Straight-line use ONLY: in a rotated loop the pipeline
// registers become PHIs and RA inserts copies that read not-yet-landed data
// (R5 failure). No loop -> no phi -> no copy.
__device__ __forceinline__ void gload(f32x4& d, const f32x4* a) {
    asm volatile("global_load_dwordx4 %0, %1, off" : "=v"(d) : "v"(a));
}

#define SB() __builtin_amdgcn_sched_barrier(0)
// Counted wait; SB right after stops compute hoisting above the wait (rule #18).
#define WAITV(n) do { asm volatile("s_waitcnt vmcnt(" #n ")" ::: "memory"); SB(); } while (0)

#define COMPV(P, G)                                    \
    do {                                               \
        hm_elem((P)[0], (G)[0], s_loss, posc, cntc);   \
        hm_elem((P)[1], (G)[1], s_loss, posc, cntc);   \
        hm_elem((P)[2], (G)[2], s_loss, posc, cntc);   \
        hm_elem((P)[3], (G)[3], s_loss, posc, cntc);   \
    } while (0)

// Steady-state phase: retire oldest chunk (8 in flight -> wait to 6), compute
// it, then refill its register set with chunk CNEXT. SB keeps the compute from
// being sunk en masse (register-pressure explosion) and the issue prompt.
#define PH_MID(SET, CNEXT)                                        \
    do {                                                          \
        WAITV(6);                                                 \
        COMPV(P##SET, G##SET);                                    \
        SB();                                                     \
        const f32x4* _pa = pp + (long long)(CNEXT) * NT;          \
        const f32x4* _ga = gg + (long long)(CNEXT) * NT;          \
        gload(P##SET, _pa);                                       \
        gload(G##SET, _ga);                                       \
    } while (0)

#define PH_TAIL(SET, WN)                                          \
    do { WAITV(WN); COMPV(P##SET, G##SET); SB(); } while (0)

__global__ void __launch_bounds__(256)
hm_loss_kernel(const f32x4* __restrict__ p4,
               const f32x4* __restrict__ g4,
               float* __restrict__ ws, long long N4) {
    long long tid = (long long)blockIdx.x * blockDim.x + threadIdx.x;
    long long NT  = (long long)gridDim.x * blockDim.x;

    float    s_loss = 0.f;
    unsigned posc = 0, cntc = 0;

    // Bench shape: N4 == 20*NT exactly (41.9M elems, 2048x256 grid).
    bool clean = (N4 == 20 * NT);

    if (clean) {
        f32x4 P0, P1, P2, P3, G0, G1, G2, G3;
        const f32x4* pp = p4 + tid;
        const f32x4* gg = g4 + tid;

        // Prologue: chunks 0..3 in flight (8 x dwordx4 = 8 KB/wave).
        gload(P0, pp);              gload(G0, gg);
        gload(P1, pp + NT);         gload(G1, gg + NT);
        gload(P2, pp + 2 * NT);     gload(G2, gg + 2 * NT);
        gload(P3, pp + 3 * NT);     gload(G3, gg + 3 * NT);

        PH_MID(0, 4);   PH_MID(1, 5);   PH_MID(2, 6);   PH_MID(3, 7);
        PH_MID(0, 8);   PH_MID(1, 9);   PH_MID(2, 10);  PH_MID(3, 11);
        PH_MID(0, 12);  PH_MID(1, 13);  PH_MID(2, 14);  PH_MID(3, 15);
        PH_MID(0, 16);  PH_MID(1, 17);  PH_MID(2, 18);  PH_MID(3, 19);

        PH_TAIL(0, 6);  PH_TAIL(1, 4);  PH_TAIL(2, 2);  PH_TAIL(3, 0);
    } else {
        for (long long i = tid; i < N4; i += NT) {
            f32x4 xp = p4[i];
            f32x4 xg = g4[i];
            COMPV(xp, xg);
        }
    }

    int lane = threadIdx.x & 63;
    float fpos = (lane == 0) ? (float)posc : 0.f;
    float fcnt = (lane == 0) ? (float)cntc : 0.f;
    block_reduce_store3(s_loss, fpos, fcnt, &ws[3 * (size_t)blockIdx.x]);
}

__device__ __forceinline__ float smooth_l1(float d) {
    float ad = fabsf(d);
    return (ad < 1.0f) ? 0.5f * d * d : ad - 0.5f;
}

__global__ void __launch_bounds__(256)
reg_loss_kernel(const float* __restrict__ wh_pred,  const float* __restrict__ wh_gt,
                const float* __restrict__ off_pred, const float* __restrict__ off_gt,
                const int* __restrict__ mask, const int* __restrict__ ind,
                float* __restrict__ ws, int BK, int K, int HW) {
    int t = blockIdx.x * blockDim.x + threadIdx.x;
    int nt = gridDim.x * blockDim.x;
    float s_wh = 0.f, s_off = 0.f, s_m = 0.f;

    for (int i = t; i < BK; i += nt) {
        int b   = i / K;
        float m = (float)mask[i];
        int idx = ind[i];
        const float* wb = wh_pred  + (size_t)b * 2 * HW;
        const float* ob = off_pred + (size_t)b * 2 * HW;
        #pragma unroll
        for (int c = 0; c < 2; ++c) {
            float gw = wb[(size_t)c * HW + idx];
            float tw = wh_gt[(size_t)i * 2 + c];
            s_wh += smooth_l1(gw * m - tw * m);

            float go = ob[(size_t)c * HW + idx];
            float to = off_gt[(size_t)i * 2 + c];
            s_off += smooth_l1(go * m - to * m);
        }
        s_m += 2.0f * m;
    }

    block_reduce_store3(s_wh, s_off, s_m, &ws[REG_OFF + 3 * (size_t)blockIdx.x]);
}

__global__ void __launch_bounds__(1024)
reduce_finalize_kernel(const float* __restrict__ ws, float* __restrict__ out) {
    float a = 0.f, b = 0.f, c = 0.f, w = 0.f, o = 0.f, m = 0.f;
    for (int i = threadIdx.x; i < NB_HM; i += 1024) {
        a += ws[3 * i + 0];
        b += ws[3 * i + 1];
        c += ws[3 * i + 2];
    }
    if (threadIdx.x < 3 * NB_REG) {
        float v = ws[REG_OFF + threadIdx.x];
        int r = threadIdx.x % 3;
        w = (r == 0) ? v : 0.f;
        o = (r == 1) ? v : 0.f;
        m = (r == 2) ? v : 0.f;
    }

    a = wave_sum(a); b = wave_sum(b); c = wave_sum(c);
    w = wave_sum(w); o = wave_sum(o); m = wave_sum(m);

    __shared__ float s[6][16];
    int lane = threadIdx.x & 63, wv = threadIdx.x >> 6;
    if (lane == 0) {
        s[0][wv] = a; s[1][wv] = b; s[2][wv] = c;
        s[3][wv] = w; s[4][wv] = o; s[5][wv] = m;
    }
    __syncthreads();
    if (threadIdx.x == 0) {
        float t[6];
        #pragma unroll
        for (int k = 0; k < 6; ++k) {
            float acc = 0.f;
            for (int q = 0; q < 16; ++q) acc += s[k][q];
            t[k] = acc;
        }
        float loss_sum = -t[0];
        float num_pos  = t[1];
        float fallback = fmaxf(t[2], 1.0f);
        float denom    = (num_pos == 0.0f) ? fallback : num_pos;
        float hm_loss  = loss_sum / denom;
        float md       = t[5] + 1e-4f;
        float wh_loss  = t[3] / md;
        float off_loss = t[4] / md;
        out[0] = hm_loss;
        out[1] = wh_loss;
        out[2] = off_loss;
        out[3] = hm_loss + 0.1f * wh_loss + off_loss;
    }
}

extern "C" void kernel_launch(void* const* d_in, const int* in_sizes, int n_in,
                              void* d_out, int out_size, void* d_ws, size_t ws_size,
                              hipStream_t stream) {
    const float* hm_pred  = (const float*)d_in[0];
    const float* hm_gt    = (const float*)d_in[1];
    const float* wh_pred  = (const float*)d_in[2];
    const float* wh_gt    = (const float*)d_in[3];
    const float* off_pred = (const float*)d_in[4];
    const float* off_gt   = (const float*)d_in[5];
    const int*   mask     = (const int*)d_in[6];
    const int*   ind      = (const int*)d_in[7];
    float*       out      = (float*)d_out;
    float*       ws       = (float*)d_ws;

    long long N  = in_sizes[0];          // B*C*H*W
    int       BK = in_sizes[6];          // B*K
    const int K  = 128;                  // per reference setup
    int       B  = BK / K;
    int       HW = in_sizes[2] / (2 * B);

    hm_loss_kernel<<<NB_HM, 256, 0, stream>>>((const f32x4*)hm_pred,
                                              (const f32x4*)hm_gt, ws, N >> 2);
    reg_loss_kernel<<<NB_REG, 256, 0, stream>>>(wh_pred, wh_gt, off_pred, off_gt,
                                                mask, ind, ws, BK, K, HW);
    reduce_finalize_kernel<<<1, 1024, 0, stream>>>(ws, out);
}